// Round 5
// baseline (962.458 us; speedup 1.0000x reference)
//
#include <hip/hip_runtime.h>
#include <math.h>

#define N_PTS  131072
#define DIM    128
#define NBOOK  4
#define KCODES 1024

#define CHUNK   32                   // codes per LDS chunk
#define PT      2                    // point tiles (32 pts each) per wave -> 64 pts/wave
#define BPTS    256                  // 4 waves * 64 points
#define CHUNK_BYTES 8320             // 4096 c_hi + 4096 c_lo + 128 cq(f32[32])
#define EPS_ACC 0.045f               // margin in acc units; quant err ~3e-3 rms
#define WL_CAP  131072

// two-level int8 quantization: v ~= (hi + lo/256) / 18
#define S1     18.0f
#define INV_S1 (1.0f/18.0f)
#define S2     4608.0f               // 18*256
#define INV1   (1.0f/324.0f)         // 1/(18*18)
#define INV2   (1.0f/82944.0f)       // 1/(18*18*256)

typedef int   i32x4  __attribute__((ext_vector_type(4)));
typedef int   i32x16 __attribute__((ext_vector_type(16)));
typedef float f32x4  __attribute__((ext_vector_type(4)));

// ws layout: cbf (4*32*8320 = 1064960 B) | csq fp32[4096] | counter | worklist
#define WS_CSQ_OFF  2359296u
#define WS_CNT_OFF  (WS_CSQ_OFF + 16384u)
#define WS_WL_OFF   (WS_CNT_OFF + 256u)

__device__ inline void quant2(float v, int& h, int& l) {
    float hf = rintf(v * S1);
    hf = fminf(fmaxf(hf, -127.f), 127.f);
    float r  = v - hf * INV_S1;
    float lf = rintf(r * S2);
    lf = fminf(fmaxf(lf, -127.f), 127.f);
    h = (int)hf; l = (int)lf;
}

__device__ inline void async_copy16(const void* g, void* l) {
    __builtin_amdgcn_global_load_lds(
        (const __attribute__((address_space(1))) void*)g,
        (__attribute__((address_space(3))) void*)l,
        16, 0, 0);
}

// ---------------- prep: codebook -> int8 A-fragments (32x32x32) + cq + csq -------------
// cbf per (b,chunk): [0,4096) c_hi frags, [4096,8192) c_lo frags, [8192,8320) cq f32[32]
// frag: s (0..3) * 1024 + lane*16; byte j: code = chunk*32 + (lane&31),
//       k = s*32 + (lane>>5)*16 + j  (same k-map used for B side -> permutation-safe)
// cq[code] = 320 - csq[code]/2  (f32)
__global__ __launch_bounds__(256)
void prep_kernel(const float* __restrict__ cb, char* __restrict__ cbf,
                 float* __restrict__ csq, int* __restrict__ counter) {
    if (blockIdx.x >= 256) {                       // csq + cq + counter blocks (16)
        int idx = (blockIdx.x - 256) * 256 + threadIdx.x;   // 0..4095
        if (idx == 0) *counter = 0;
        const float4* p = (const float4*)(cb + (size_t)idx * DIM);
        float s = 0.f;
#pragma unroll
        for (int i = 0; i < DIM / 4; ++i) {
            float4 v = p[i];
            s += v.x * v.x + v.y * v.y + v.z * v.z + v.w * v.w;
        }
        csq[idx] = s;
        int b = idx >> 10, k = idx & 1023;
        *(float*)(cbf + (size_t)(b * 32 + (k >> 5)) * CHUNK_BYTES + 8192 + (k & 31) * 4)
            = 320.0f - 0.5f * s;
        return;
    }
    int t     = blockIdx.x * 256 + threadIdx.x;    // 0..65535
    int lane  = t & 63;
    int s     = (t >> 6) & 3;
    int plane = (t >> 8) & 1;
    int bc    = t >> 9;                            // 0..127  (b*32 + chunk)
    int code  = (bc & 31) * CHUNK + (lane & 31);
    int b     = bc >> 5;
    int kb    = s * 32 + (lane >> 5) * 16;

    const float* row = cb + ((size_t)b * KCODES + code) * DIM + kb;
    float4 v0 = ((const float4*)row)[0];
    float4 v1 = ((const float4*)row)[1];
    float4 v2 = ((const float4*)row)[2];
    float4 v3 = ((const float4*)row)[3];
    float vals[16] = {v0.x, v0.y, v0.z, v0.w, v1.x, v1.y, v1.z, v1.w,
                      v2.x, v2.y, v2.z, v2.w, v3.x, v3.y, v3.z, v3.w};
    unsigned o[4] = {0, 0, 0, 0};
#pragma unroll
    for (int j = 0; j < 16; ++j) {
        int h, l;
        quant2(vals[j], h, l);
        int q = plane ? l : h;
        o[j >> 2] |= ((unsigned)(q & 255)) << ((j & 3) * 8);
    }
    *(uint4*)(cbf + (size_t)bc * CHUNK_BYTES + plane * 4096 + s * 1024 + lane * 16)
        = make_uint4(o[0], o[1], o[2], o[3]);
}

// ---------------- main: dbuf LDS, int8 MFMA (24/chunk vs 50 bf16), in-phase epilogue ---
// grid (512, 2): block y handles books {2y, 2y+1} as one 64-chunk stream
__global__ __launch_bounds__(256, 2)
void argmin_mfma_kernel(const float* __restrict__ x,
                        const char* __restrict__ cbf,
                        int* __restrict__ out,
                        int* __restrict__ counter,
                        int* __restrict__ worklist) {
    __shared__ i32x4 ldsv[2 * CHUNK_BYTES / 16];   // 16640 B (two 8.3 KB buffers)

    const int tid  = threadIdx.x;
    const int lane = tid & 63;
    const int w    = tid >> 6;
    const int n0   = blockIdx.x * BPTS;
    const int col  = lane & 31;
    const int kh   = lane >> 5;

    const char* src0 = cbf + (size_t)(blockIdx.y * 64) * CHUNK_BYTES;
    char* ldsb = (char*)ldsv;

    auto issue = [&](int c) {                      // stage chunk c -> buf[c&1]
        const char* src = src0 + (size_t)c * CHUNK_BYTES;
        char* dst = ldsb + (c & 1) * CHUNK_BYTES;
#pragma unroll
        for (int i = 0; i < 2; ++i)
            async_copy16(src + i * 4096 + tid * 16, dst + i * 4096 + w * 1024);
        if (w == 0 && lane < 8)
            async_copy16(src + 8192 + lane * 16, dst + 8192);
    };

    issue(0);                                      // chunk 0 in flight during x-quant

    // ---- B fragments (points), int8 hi+lo, in regs (overlaps chunk-0 staging) ----
    // col = point-in-tile, k = s*32 + kh*16 + j  (matches A-side k-map)
    i32x4 xh[PT][4], xl[PT][4];
#pragma unroll
    for (int pt = 0; pt < PT; ++pt) {
        const float* xrow = x + (size_t)(n0 + w * 64 + pt * 32 + col) * DIM;
#pragma unroll
        for (int s = 0; s < 4; ++s) {
            const float* p = xrow + s * 32 + kh * 16;
            float4 v0 = ((const float4*)p)[0];
            float4 v1 = ((const float4*)p)[1];
            float4 v2 = ((const float4*)p)[2];
            float4 v3 = ((const float4*)p)[3];
            float vals[16] = {v0.x, v0.y, v0.z, v0.w, v1.x, v1.y, v1.z, v1.w,
                              v2.x, v2.y, v2.z, v2.w, v3.x, v3.y, v3.z, v3.w};
            unsigned oh[4] = {0, 0, 0, 0}, ol[4] = {0, 0, 0, 0};
#pragma unroll
            for (int j = 0; j < 16; ++j) {
                int h, l;
                quant2(vals[j], h, l);
                oh[j >> 2] |= ((unsigned)(h & 255)) << ((j & 3) * 8);
                ol[j >> 2] |= ((unsigned)(l & 255)) << ((j & 3) * 8);
            }
            i32x4 hv = {(int)oh[0], (int)oh[1], (int)oh[2], (int)oh[3]};
            i32x4 lv = {(int)ol[0], (int)ol[1], (int)ol[2], (int)ol[3]};
            xh[pt][s] = hv;
            xl[pt][s] = lv;
        }
    }

    unsigned b1p[PT], b2p[PT];
    int bchunk[PT];
#pragma unroll
    for (int pt = 0; pt < PT; ++pt) { b1p[pt] = 0u; b2p[pt] = 0u; bchunk[pt] = 0; }

    // one chunk: 24 int8 MFMAs + fused convert/pack/top-2 (no deferral -> low VGPR)
    auto chunk_step = [&](const char* A, int cc) {
        f32x4 cqv[4];                              // cq rows {0..3,8..11,16..19,24..27}+4kh
#pragma unroll
        for (int g = 0; g < 4; ++g)
            cqv[g] = *(const f32x4*)(A + 8192 + kh * 16 + g * 32);

        i32x16 hh[PT], xx[PT];
#pragma unroll
        for (int pt = 0; pt < PT; ++pt)
#pragma unroll
            for (int r = 0; r < 16; ++r) { hh[pt][r] = 0; xx[pt][r] = 0; }

#pragma unroll
        for (int s = 0; s < 4; ++s) {
            i32x4 chi = *(const i32x4*)(A + s * 1024 + lane * 16);
            i32x4 clo = *(const i32x4*)(A + 4096 + s * 1024 + lane * 16);
#pragma unroll
            for (int pt = 0; pt < PT; ++pt) {
                hh[pt] = __builtin_amdgcn_mfma_i32_32x32x32_i8(chi, xh[pt][s], hh[pt], 0, 0, 0);
                xx[pt] = __builtin_amdgcn_mfma_i32_32x32x32_i8(clo, xh[pt][s], xx[pt], 0, 0, 0);
                xx[pt] = __builtin_amdgcn_mfma_i32_32x32x32_i8(chi, xl[pt][s], xx[pt], 0, 0, 0);
            }
        }

        int ci = cc & 31;
#pragma unroll
        for (int pt = 0; pt < PT; ++pt) {          // v = hh/324 + xx/82944 + (320 - csq/2)
            unsigned prev = b1p[pt], p1v = prev, p2v = b2p[pt];
#pragma unroll
            for (int r = 0; r < 16; r += 2) {
                float va = fmaf((float)hh[pt][r], INV1,
                                fmaf((float)xx[pt][r], INV2, cqv[r >> 2][r & 3]));
                float vb = fmaf((float)hh[pt][r + 1], INV1,
                                fmaf((float)xx[pt][r + 1], INV2, cqv[r >> 2][(r & 3) + 1]));
                unsigned pa = (__float_as_uint(va) & 0xFFFFFFE0u) | (31u - (unsigned)r);
                unsigned pb = (__float_as_uint(vb) & 0xFFFFFFE0u) | (30u - (unsigned)r);
                unsigned hi = pa > pb ? pa : pb;
                unsigned lo = pa < pb ? pa : pb;
                unsigned t2 = hi < p1v ? hi : p1v;
                unsigned m  = lo > t2 ? lo : t2;
                p2v = p2v > m ? p2v : m;           // -> v_max3
                p1v = p1v > hi ? p1v : hi;
            }
            bchunk[pt] = (p1v != prev) ? ci : bchunk[pt];
            b1p[pt] = p1v; b2p[pt] = p2v;
        }
    };

    auto finalize = [&](int book) {
        int b = blockIdx.y * 2 + book;
#pragma unroll
        for (int pt = 0; pt < PT; ++pt) {
            unsigned r = 31u - (b1p[pt] & 31u);    // leaf 0..15
            float m1 = __uint_as_float(b1p[pt] & 0xFFFFFFE0u);
            float m2 = __uint_as_float(b2p[pt] & 0xFFFFFFE0u);
            int row = (int)((r & 3u) + 8u * (r >> 2)) + 4 * kh;
            int code = bchunk[pt] * CHUNK + row;
            float om1 = __shfl_xor(m1, 32);
            float om2 = __shfl_xor(m2, 32);
            int   oc  = __shfl_xor(code, 32);
            bool take = (om1 > m1) || (om1 == m1 && oc < code);
            float nm2 = fmaxf(fminf(m1, om1), fmaxf(m2, om2));
            if (take) { m1 = om1; code = oc; }
            m2 = nm2;
            if (lane < 32) {
                int point = n0 + w * 64 + pt * 32 + col;
                out[point * NBOOK + b] = code;
                if (m1 - m2 < EPS_ACC) {
                    int pos = atomicAdd(counter, 1);
                    if (pos < WL_CAP) worklist[pos] = point * NBOOK + b;
                }
            }
            b1p[pt] = 0u; b2p[pt] = 0u; bchunk[pt] = 0;
        }
    };

    __syncthreads();                               // chunk 0 visible

    for (int c = 0; c < 64; ++c) {
        if (c + 1 < 64) issue(c + 1);              // stage next into other buffer
        chunk_step(ldsb + (c & 1) * CHUNK_BYTES, c);
        if (c == 31) finalize(0);
        __syncthreads();                           // staging done; reads done
    }
    finalize(1);
}

// ---------------- fallback: exact fp32 recompute for small-margin items ----------------
__global__ __launch_bounds__(256)
void exact_kernel(const float* __restrict__ x,
                  const float* __restrict__ cb,
                  const float* __restrict__ csq,
                  const int* __restrict__ counter,
                  const int* __restrict__ worklist,
                  int* __restrict__ out) {
    __shared__ float xs[DIM];
    __shared__ float rbest[4];
    __shared__ int   ribest[4];

    int nitems = *counter;
    if (nitems > WL_CAP) nitems = WL_CAP;

    for (int item = blockIdx.x; item < nitems; item += gridDim.x) {
        int nb = worklist[item];
        int n = nb >> 2, b = nb & 3;
        __syncthreads();
        if (threadIdx.x < 32) {
            float4 v = ((const float4*)(x + (size_t)n * DIM))[threadIdx.x];
            *(float4*)&xs[threadIdx.x * 4] = v;
        }
        __syncthreads();

        const float* cbb = cb + (size_t)b * KCODES * DIM;
        const float* crow[4];
#pragma unroll
        for (int kk = 0; kk < 4; ++kk)
            crow[kk] = cbb + (size_t)(kk * 256 + threadIdx.x) * DIM;

        float dots[4] = {0.f, 0.f, 0.f, 0.f};
#pragma unroll 8
        for (int d = 0; d < DIM; d += 4) {
            float4 xv = *(const float4*)&xs[d];
#pragma unroll
            for (int kk = 0; kk < 4; ++kk) {
                float4 cv = *(const float4*)(crow[kk] + d);
                dots[kk] += xv.x * cv.x + xv.y * cv.y + xv.z * cv.z + xv.w * cv.w;
            }
        }

        float bd = 3.4e38f;
        int   bi = 0;
#pragma unroll
        for (int kk = 0; kk < 4; ++kk) {
            int k = kk * 256 + threadIdx.x;
            float dist = csq[b * KCODES + k] - 2.f * dots[kk];
            if (dist < bd) { bd = dist; bi = k; }
        }
        for (int off = 1; off < 64; off <<= 1) {
            float od = __shfl_xor(bd, off);
            int   oi = __shfl_xor(bi, off);
            if (od < bd || (od == bd && oi < bi)) { bd = od; bi = oi; }
        }
        int w = threadIdx.x >> 6;
        if ((threadIdx.x & 63) == 0) { rbest[w] = bd; ribest[w] = bi; }
        __syncthreads();
        if (threadIdx.x == 0) {
            float fb = rbest[0]; int fi = ribest[0];
            for (int i = 1; i < 4; ++i) {
                if (rbest[i] < fb || (rbest[i] == fb && ribest[i] < fi)) {
                    fb = rbest[i]; fi = ribest[i];
                }
            }
            out[nb] = fi;
        }
    }
}

extern "C" void kernel_launch(void* const* d_in, const int* in_sizes, int n_in,
                              void* d_out, int out_size, void* d_ws, size_t ws_size,
                              hipStream_t stream) {
    const float* x  = (const float*)d_in[0];   // [N, D] fp32
    const float* cb = (const float*)d_in[1];   // [B, K, D] fp32
    int* out = (int*)d_out;                    // [N, B] int32

    char* ws = (char*)d_ws;
    char*  cbf      = ws;
    float* csq      = (float*)(ws + WS_CSQ_OFF);
    int*   counter  = (int*)(ws + WS_CNT_OFF);
    int*   worklist = (int*)(ws + WS_WL_OFF);

    prep_kernel<<<272, 256, 0, stream>>>(cb, cbf, csq, counter);

    argmin_mfma_kernel<<<dim3(N_PTS / BPTS, 2), 256, 0, stream>>>(x, cbf, out, counter, worklist);

    exact_kernel<<<1024, 256, 0, stream>>>(x, cb, csq, counter, worklist, out);
}